// Round 2
// baseline (214.981 us; speedup 1.0000x reference)
//
#include <hip/hip_runtime.h>

#define BATCH    8192
#define FEAT     256
#define NCLASS   100000
#define EPS_C    1e-6f

#define NC_ELEMS (NCLASS * FEAT)          // 25,600,000 floats
#define NVEC     (NC_ELEMS / 4)           // 6,400,000 float4s
#define COPY_BLOCKS (NVEC / 256)          // 25,000 blocks

// ONE block: clear all heads, barrier, build per-class linked lists.
// Replaces hipMemsetAsync + build_kernel (saves one dispatch + gap).
__global__ void build1_kernel(const int* __restrict__ target,
                              int* __restrict__ head,
                              int* __restrict__ next) {
    int t = threadIdx.x;
    for (int c = t; c < NCLASS; c += 1024) head[c] = -1;
    __syncthreads();                       // stores drained (s_waitcnt) before atomics
    for (int b = t; b < BATCH; b += 1024)
        next[b] = atomicExch(&head[target[b]], b);
}

// One wave per SAMPLE; the wave whose sample is the list head owns the class:
// walks the list, writes per-sample loss partials, and writes the FINAL
// (shifted) row into out. Runs BEFORE the copy; copy skips these rows.
__global__ void update_kernel(const float* __restrict__ centers,
                              const float* __restrict__ features,
                              const int* __restrict__ target,
                              const int* __restrict__ head,
                              const int* __restrict__ next,
                              float* __restrict__ partials,
                              float* __restrict__ out) {
    int wv = (blockIdx.x * blockDim.x + threadIdx.x) >> 6;   // sample id 0..8191
    int l  = threadIdx.x & 63;
    int r  = target[wv];
    if (head[r] != wv) return;            // only the head sample's wave proceeds

    const float4 c4 = ((const float4*)(centers + (size_t)r * FEAT))[l];
    float4 sumf = {0.f, 0.f, 0.f, 0.f};
    int n = 0;
    for (int s = wv; s != -1; s = next[s]) {
        float4 f4 = ((const float4*)(features + (size_t)s * FEAT))[l];
        sumf.x += f4.x; sumf.y += f4.y; sumf.z += f4.z; sumf.w += f4.w;
        float dx = c4.x - f4.x, dy = c4.y - f4.y;
        float dz = c4.z - f4.z, dw = c4.w - f4.w;
        float sq = dx*dx + dy*dy + dz*dz + dw*dw;
        #pragma unroll
        for (int off = 32; off > 0; off >>= 1) sq += __shfl_down(sq, off, 64);
        if (l == 0) partials[s] = sq;     // each sample is in exactly one list
        n++;
    }
    float nf  = (float)n;
    float inv = 1.0f / (nf + EPS_C);
    // new = c - (n*c - sum_f)/(n+eps)
    float nx = c4.x - (nf * c4.x - sumf.x) * inv;
    float ny = c4.y - (nf * c4.y - sumf.y) * inv;
    float nz = c4.z - (nf * c4.z - sumf.z) * inv;
    float nw = c4.w - (nf * c4.w - sumf.w) * inv;

    // shifted row write: covers out elements [r*256+1 .. (r+1)*256]
    float* orow = out + 1 + (size_t)r * FEAT + 4 * l;
    orow[0] = nx; orow[1] = ny; orow[2] = nz; orow[3] = nw;
}

// Streaming copy of centers -> out shifted +1, SKIPPING rows update wrote.
// Wave w of block B owns out elements [r*256 .. r*256+255], r = B*4+w:
//   - out[r*256]      = nc[r*256-1] (prev row's last)  -> skip iff touched(r-1)
//   - out[r*256+1..]  = nc row r's first 255           -> skip iff touched(r)
// Block 0 also reduces the 8192 loss partials into out[0] (overlapped, free).
__global__ void copy_kernel(const float* __restrict__ centers,
                            const int* __restrict__ head,
                            const float* __restrict__ partials,
                            float* __restrict__ out) {
    int t = threadIdx.x;
    int w = t >> 6;
    int l = t & 63;
    size_t i = (size_t)blockIdx.x * 256 + t;          // float4 index into out
    int r = (int)(i >> 6);                            // center row for this wave
    float4 c4 = ((const float4*)centers)[i];          // nc elements 4i..4i+3 (old)
    bool tr = (head[r] != -1);                        // wave-uniform
    float pw = __shfl_up(c4.w, 1, 64);                // nc[4i-1] for lanes >= 1

    if (l == 0) {
        bool tp = (r > 0) && (head[r - 1] != -1);
        if (r > 0 && !tp) {
            float e0 = centers[(size_t)r * FEAT - 1]; // prev row's last elem (old)
            if (!tr) {
                float4 ov = {e0, c4.x, c4.y, c4.z};
                ((float4*)out)[i] = ov;
            } else {
                out[4 * i] = e0;                      // row r handled by update
            }
        } else if (!tr) {
            // prev row touched (update wrote out[4i]) or r==0 (loss slot):
            // write only this row's 3 elements
            out[4 * i + 1] = c4.x; out[4 * i + 2] = c4.y; out[4 * i + 3] = c4.z;
        }
    } else if (!tr) {
        float4 ov = {pw, c4.x, c4.y, c4.z};
        ((float4*)out)[i] = ov;
    }

    // tail: out[NC_ELEMS] = nc[NC_ELEMS-1]; update covers it if last row touched
    if (blockIdx.x == COPY_BLOCKS - 1 && t == 255 && !tr) out[NC_ELEMS] = c4.w;

    // loss reduction in block 0 only (runs alongside the big stream)
    if (blockIdx.x == 0) {
        float s = 0.0f;
        for (int k = t; k < BATCH; k += 256) s += partials[k];
        #pragma unroll
        for (int off = 32; off > 0; off >>= 1) s += __shfl_down(s, off, 64);
        __shared__ float red[4];
        if (l == 0) red[w] = s;
        __syncthreads();
        if (t == 0)
            out[0] = (red[0] + red[1] + red[2] + red[3]) / (float)(BATCH * FEAT);
    }
}

extern "C" void kernel_launch(void* const* d_in, const int* in_sizes, int n_in,
                              void* d_out, int out_size, void* d_ws, size_t ws_size,
                              hipStream_t stream) {
    const float* features = (const float*)d_in[0];
    const int*   target   = (const int*)d_in[1];
    const float* centers  = (const float*)d_in[2];
    float* out = (float*)d_out;

    int*   head     = (int*)d_ws;                  // 100000 ints
    int*   next     = head + NCLASS;               // 8192 ints
    float* partials = (float*)(next + BATCH);      // 8192 floats

    build1_kernel<<<1, 1024, 0, stream>>>(target, head, next);
    update_kernel<<<BATCH / 4, 256, 0, stream>>>(centers, features, target,
                                                 head, next, partials, out);
    copy_kernel<<<COPY_BLOCKS, 256, 0, stream>>>(centers, head, partials, out);
}

// Round 3
// 201.365 us; speedup vs baseline: 1.0676x; 1.0676x over previous
//
#include <hip/hip_runtime.h>

#define BATCH   8192
#define FEAT    256
#define NCLASS  100000
#define EPS_C   1e-6f

#define NC_ELEMS (NCLASS * FEAT)          // 25,600,000
#define NVEC (NC_ELEMS / 4)               // 6,400,000 float4s
#define FUSED_BLOCKS (NVEC / 256)         // 25,000 blocks; each covers 4 rows

// Tiny: build per-class linked lists. head memset to -1 beforehand.
__global__ void build_kernel(const int* __restrict__ target,
                             int* __restrict__ head,
                             int* __restrict__ next) {
    int b = blockIdx.x * blockDim.x + threadIdx.x;
    if (b < BATCH) next[b] = atomicExch(&head[target[b]], b);
}

// One wave per center row (4 independent waves / 256-thread block).
// Untouched row: shifted copy. Touched row: walk the class list, compute
// updated row + per-sample loss partials. The +1-float output shift is
// handled entirely in-register: each wave writes out indices
// [r*256+1 .. (r+1)*256] — lane l>=1 stores float4 {shfl_up(n.w), n.x,n.y,n.z}
// (16B-aligned), lane 0 stores 3 scalars, lane 63 stores the right-boundary
// element (r+1)*256. Every out element is written by exactly one lane of the
// wave that computed it: no LDS, no __syncthreads, no boundary recompute.
__global__ void fused_kernel(const float* __restrict__ centers,
                             const float* __restrict__ features,
                             const int* __restrict__ head,
                             const int* __restrict__ next,
                             float* __restrict__ partials,
                             float* __restrict__ out /* d_out base */) {
    int w = threadIdx.x >> 6;             // wave 0..3
    int l = threadIdx.x & 63;             // lane
    int r = blockIdx.x * 4 + w;           // center row for this wave

    const float4 c4 = ((const float4*)(centers + (size_t)r * FEAT))[l];
    float4 n4 = c4;
    int h = head[r];
    if (h != -1) {
        float4 sumf = {0.f, 0.f, 0.f, 0.f};
        int n = 0;
        for (int s = h; s != -1; s = next[s]) {
            float4 f4 = ((const float4*)(features + (size_t)s * FEAT))[l];
            sumf.x += f4.x; sumf.y += f4.y; sumf.z += f4.z; sumf.w += f4.w;
            float dx = c4.x - f4.x, dy = c4.y - f4.y;
            float dz = c4.z - f4.z, dw = c4.w - f4.w;
            float sq = dx*dx + dy*dy + dz*dz + dw*dw;
            #pragma unroll
            for (int off = 32; off > 0; off >>= 1) sq += __shfl_down(sq, off, 64);
            if (l == 0) partials[s] = sq;   // each sample is in exactly one list
            n++;
        }
        float nf = (float)n;
        float inv = 1.0f / (nf + EPS_C);
        // new = c - (n*c - sum_f)/(n+eps)
        n4.x = c4.x - (nf * c4.x - sumf.x) * inv;
        n4.y = c4.y - (nf * c4.y - sumf.y) * inv;
        n4.z = c4.z - (nf * c4.z - sumf.z) * inv;
        n4.w = c4.w - (nf * c4.w - sumf.w) * inv;
    }

    // shifted store, in-register
    float pw = __shfl_up(n4.w, 1, 64);    // new nc[r*256 + 4l - 1] for l>=1
    if (l > 0) {
        float4 ov = {pw, n4.x, n4.y, n4.z};
        ((float4*)out)[(size_t)r * 64 + l];   // (address check: dword r*256+4l)
        ((float4*)out)[(size_t)r * 64 + l] = ov;
    } else {
        // out[r*256+1..3] = new nc[r*256+0..2]; out[0] itself is the loss slot
        size_t base = (size_t)r * FEAT;
        out[base + 1] = n4.x;
        out[base + 2] = n4.y;
        out[base + 3] = n4.z;
    }
    if (l == 63) {
        // right boundary: out[(r+1)*256] = new nc[(r+1)*256 - 1].
        // For r == NCLASS-1 this is exactly the tail element out[NC_ELEMS].
        out[(size_t)(r + 1) * FEAT] = n4.w;
    }
}

__global__ void finalize_kernel(const float* __restrict__ partials,
                                float* __restrict__ out0) {
    float s = 0.0f;
    for (int i = threadIdx.x; i < BATCH; i += 256) s += partials[i];
    #pragma unroll
    for (int off = 32; off > 0; off >>= 1) s += __shfl_down(s, off, 64);
    __shared__ float red[4];
    int wave = threadIdx.x >> 6;
    int lane = threadIdx.x & 63;
    if (lane == 0) red[wave] = s;
    __syncthreads();
    if (threadIdx.x == 0) {
        out0[0] = (red[0] + red[1] + red[2] + red[3]) / (float)(BATCH * FEAT);
    }
}

extern "C" void kernel_launch(void* const* d_in, const int* in_sizes, int n_in,
                              void* d_out, int out_size, void* d_ws, size_t ws_size,
                              hipStream_t stream) {
    const float* features = (const float*)d_in[0];
    const int*   target   = (const int*)d_in[1];
    const float* centers  = (const float*)d_in[2];
    float* out = (float*)d_out;

    int*   head     = (int*)d_ws;                                  // 100000 ints
    int*   next     = head + NCLASS;                               // 8192 ints
    float* partials = (float*)(next + BATCH);                      // 8192 floats

    hipMemsetAsync(head, 0xFF, NCLASS * sizeof(int), stream);      // head = -1
    build_kernel<<<(BATCH + 255) / 256, 256, 0, stream>>>(target, head, next);
    fused_kernel<<<FUSED_BLOCKS, 256, 0, stream>>>(centers, features, head, next,
                                                   partials, out);
    finalize_kernel<<<1, 256, 0, stream>>>(partials, out);
}